// Round 6
// baseline (128.325 us; speedup 1.0000x reference)
//
#include <hip/hip_runtime.h>

#define NTOK 49
#define NH 4
#define HD 32
#define CIN 384
#define NW 64
#define NPAD 64
#define SCALE_F 0.1767766952966369f

typedef _Float16 f16x8 __attribute__((ext_vector_type(8)));
typedef float f32x16 __attribute__((ext_vector_type(16)));
typedef __fp16 fp16x2 __attribute__((ext_vector_type(2)));

__device__ __forceinline__ unsigned int pkh(float a, float b) {
    fp16x2 h = __builtin_amdgcn_cvt_pkrtz(a, b);
    return __builtin_bit_cast(unsigned int, h);
}

// cmM[w*4+h][i][j] = mask[h][i][j] + rot[w][i][j], padded to 64x64:
// j>=49 -> -1e30 (kills padded keys), else i>=49 -> 0 (rows never stored).
__global__ __launch_bounds__(64) void prep_cmask(
    const float* __restrict__ mask,
    const float* __restrict__ rot,
    float* __restrict__ cmM)
{
    const int wh = blockIdx.x;          // w*4 + h
    const int w = wh >> 2, h = wh & 3;
    const int j = threadIdx.x;          // 0..63
    for (int i = 0; i < NPAD; ++i) {
        float v;
        if (j >= NTOK) v = -1e30f;
        else if (i >= NTOK) v = 0.f;
        else v = mask[(h * NTOK + i) * NTOK + j] + rot[(w * NTOK + i) * NTOK + j];
        cmM[((size_t)wh * NPAD + i) * NPAD + j] = v;
    }
}

// One wave per (b,h). S^T = K*Q^T (C-layout: col=i=lane&31, row=j=(r&3)+8*(r>>2)+4*hl).
// Query-halves (it) processed sequentially to halve register liveness.
// V fragments prefetched before the barrier (latency hides under staging drain).
template<bool USE_CM>
__global__ __launch_bounds__(64) void win_attn_mfma(
    const float* __restrict__ qkv,
    const float* __restrict__ mask,
    const float* __restrict__ rot,
    const float* __restrict__ cmM,
    float* __restrict__ out)
{
    const int h = blockIdx.x & 3;
    const int b = blockIdx.x >> 2;
    const int w = b & (NW - 1);
    const int lane = threadIdx.x;
    const int l31 = lane & 31;
    const int hl = lane >> 5;

    __shared__ _Float16 Qs[NPAD * HD];   // rows >= 49 zeroed
    __shared__ _Float16 Ks[NPAD * HD];

    const float* base = qkv + (size_t)b * (NTOK * CIN) + h * HD;

    // ---- stage Q (pre-scaled) and K as f16 into LDS ----
    #pragma unroll
    for (int t8 = 0; t8 < 8; ++t8) {
        const int idx = lane + t8 * 64;    // 0..511
        const int n = idx >> 3;            // row 0..63
        const int c = idx & 7;             // float4 chunk
        float4 fq = make_float4(0.f, 0.f, 0.f, 0.f);
        float4 fk = fq;
        if (n < NTOK) {
            const float* p = base + n * CIN + c * 4;
            fq = *reinterpret_cast<const float4*>(p);
            fk = *reinterpret_cast<const float4*>(p + 128);
        }
        uint2 uq, uk;
        uq.x = pkh(fq.x * SCALE_F, fq.y * SCALE_F);
        uq.y = pkh(fq.z * SCALE_F, fq.w * SCALE_F);
        uk.x = pkh(fk.x, fk.y);
        uk.y = pkh(fk.z, fk.w);
        *reinterpret_cast<uint2*>(&Qs[n * HD + c * 4]) = uq;
        *reinterpret_cast<uint2*>(&Ks[n * HD + c * 4]) = uk;
    }

    // ---- prefetch V B-fragments (issued before barrier drain; T14) ----
    uint4 vb[4];
    {
        const float* vbase = qkv + (size_t)b * (NTOK * CIN) + 256 + h * HD + l31;
        #pragma unroll
        for (int ks = 0; ks < 4; ++ks) {
            unsigned dd[4];
            #pragma unroll
            for (int ep = 0; ep < 4; ++ep) {
                const int j0 = 16 * ks + 8 * hl + 2 * ep;
                const float v0 = (j0     < NTOK) ? vbase[(size_t)j0 * CIN]       : 0.f;
                const float v1 = (j0 + 1 < NTOK) ? vbase[(size_t)(j0 + 1) * CIN] : 0.f;
                dd[ep] = pkh(v0, v1);
            }
            vb[ks] = make_uint4(dd[0], dd[1], dd[2], dd[3]);
        }
    }

    __syncthreads();

    // ---- K fragments (shared across both query halves) ----
    f16x8 ka[2][2];
    #pragma unroll
    for (int t = 0; t < 2; ++t) {
        #pragma unroll
        for (int ks = 0; ks < 2; ++ks) {
            ka[t][ks] = *reinterpret_cast<const f16x8*>(&Ks[(l31 + 32 * t) * HD + ks * 16 + hl * 8]);
        }
    }

    #pragma unroll 1
    for (int it = 0; it < 2; ++it) {
        const int i = l31 + 32 * it;
        const f16x8 qa0 = *reinterpret_cast<const f16x8*>(&Qs[i * HD + hl * 8]);
        const f16x8 qa1 = *reinterpret_cast<const f16x8*>(&Qs[i * HD + 16 + hl * 8]);

        // combined-mask values for this query half
        float cmv[2][16];
        if (USE_CM) {
            const float* cmRow = cmM + ((size_t)(w * 4 + h) * NPAD + i) * NPAD;
            #pragma unroll
            for (int jt = 0; jt < 2; ++jt) {
                #pragma unroll
                for (int rq = 0; rq < 4; ++rq) {
                    const float4 c = *reinterpret_cast<const float4*>(&cmRow[32 * jt + 8 * rq + 4 * hl]);
                    cmv[jt][4 * rq + 0] = c.x;
                    cmv[jt][4 * rq + 1] = c.y;
                    cmv[jt][4 * rq + 2] = c.z;
                    cmv[jt][4 * rq + 3] = c.w;
                }
            }
        } else {
            #pragma unroll
            for (int jt = 0; jt < 2; ++jt) {
                #pragma unroll
                for (int r = 0; r < 16; ++r) {
                    const int j = (r & 3) + 8 * (r >> 2) + 4 * hl + 32 * jt;
                    float v;
                    if (j >= NTOK) v = -1e30f;
                    else if (i >= NTOK) v = 0.f;
                    else v = mask[(h * NTOK + i) * NTOK + j] + rot[(w * NTOK + i) * NTOK + j];
                    cmv[jt][r] = v;
                }
            }
        }

        // ---- S^T = K * Q^T for this half ----
        f32x16 acc[2];
        __builtin_amdgcn_s_setprio(1);
        #pragma unroll
        for (int jt = 0; jt < 2; ++jt) {
            f32x16 a;
            #pragma unroll
            for (int r = 0; r < 16; ++r) a[r] = 0.f;
            a = __builtin_amdgcn_mfma_f32_32x32x16_f16(ka[jt][0], qa0, a, 0, 0, 0);
            a = __builtin_amdgcn_mfma_f32_32x32x16_f16(ka[jt][1], qa1, a, 0, 0, 0);
            acc[jt] = a;
        }
        __builtin_amdgcn_s_setprio(0);

        // ---- + mask, softmax over j (32 lane-local + lane^32 partner) ----
        float m = -3e38f;
        #pragma unroll
        for (int jt = 0; jt < 2; ++jt) {
            #pragma unroll
            for (int r = 0; r < 16; ++r) {
                acc[jt][r] += cmv[jt][r];
                m = fmaxf(m, acc[jt][r]);
            }
        }
        m = fmaxf(m, __shfl_xor(m, 32));
        float s = 0.f;
        #pragma unroll
        for (int jt = 0; jt < 2; ++jt) {
            #pragma unroll
            for (int r = 0; r < 16; ++r) {
                const float e = __expf(acc[jt][r] - m);
                acc[jt][r] = e;
                s += e;
            }
        }
        s += __shfl_xor(s, 32);
        const float inv = 1.f / s;
        #pragma unroll
        for (int jt = 0; jt < 2; ++jt) {
            #pragma unroll
            for (int r = 0; r < 16; ++r) acc[jt][r] *= inv;
        }

        // ---- O = P * V for this half ----
        f32x16 oacc;
        #pragma unroll
        for (int r = 0; r < 16; ++r) oacc[r] = 0.f;

        #pragma unroll
        for (int ks = 0; ks < 4; ++ks) {
            const int jt = ks >> 1;
            const int r8 = 8 * (ks & 1);
            const unsigned lo0 = pkh(acc[jt][r8 + 0], acc[jt][r8 + 1]);
            const unsigned lo1 = pkh(acc[jt][r8 + 2], acc[jt][r8 + 3]);
            const unsigned hi0 = pkh(acc[jt][r8 + 4], acc[jt][r8 + 5]);
            const unsigned hi1 = pkh(acc[jt][r8 + 6], acc[jt][r8 + 7]);
            const unsigned x0 = hl ? lo0 : hi0;
            const unsigned x1 = hl ? lo1 : hi1;
            const unsigned y0 = (unsigned)__shfl_xor((int)x0, 32);
            const unsigned y1 = (unsigned)__shfl_xor((int)x1, 32);
            uint4 pu;
            pu.x = hl ? y0 : lo0;
            pu.y = hl ? y1 : lo1;
            pu.z = hl ? hi0 : y0;
            pu.w = hl ? hi1 : y1;
            const f16x8 pa  = __builtin_bit_cast(f16x8, pu);
            const f16x8 vbk = __builtin_bit_cast(f16x8, vb[ks]);
            oacc = __builtin_amdgcn_mfma_f32_32x32x16_f16(pa, vbk, oacc, 0, 0, 0);
        }

        // ---- store this half: O[i][d], d = l31 ----
        float* obase = out + (size_t)b * NTOK * (NH * HD) + h * HD + l31;
        #pragma unroll
        for (int r = 0; r < 16; ++r) {
            const int io = (r & 3) + 8 * (r >> 2) + 4 * hl + 32 * it;
            if (io < NTOK) obase[(size_t)io * (NH * HD)] = oacc[r];
        }
    }
}

extern "C" void kernel_launch(void* const* d_in, const int* in_sizes, int n_in,
                              void* d_out, int out_size, void* d_ws, size_t ws_size,
                              hipStream_t stream) {
    const float* qkv  = (const float*)d_in[0];
    const float* mask = (const float*)d_in[1];
    const float* rot  = (const float*)d_in[2];
    float* out = (float*)d_out;

    const int Btot = in_sizes[0] / (NTOK * CIN);  // 4096
    dim3 grid(Btot * NH);

    const size_t cm_bytes = (size_t)NW * NH * NPAD * NPAD * sizeof(float);  // 4 MiB
    if (ws_size >= cm_bytes && d_ws != nullptr) {
        float* cmM = (float*)d_ws;
        prep_cmask<<<dim3(NW * NH), 64, 0, stream>>>(mask, rot, cmM);
        win_attn_mfma<true><<<grid, 64, 0, stream>>>(qkv, mask, rot, cmM, out);
    } else {
        win_attn_mfma<false><<<grid, 64, 0, stream>>>(qkv, mask, rot, nullptr, out);
    }
}